// Round 15
// baseline (197.796 us; speedup 1.0000x reference)
//
#include <hip/hip_runtime.h>
#include <math.h>

#define NCL 21
#define CIN 256
#define HW 4096
#define PADK 24
#define NB 2

static __device__ __forceinline__ float fastrcp(float x) {
  return __builtin_amdgcn_rcpf(x);
}

// ---------------------------------------------------------------------------
// Kernel A (v2, R14 — kept; corr8-clock-normalized it saved ~7 us): f1/f2 =
// 1x1 conv, f1 pre-scaled by 1/sqrt(21). 1024 blocks = 4 blocks/CU; 32 chunks
// of 8 channels; wave-butterfly + small-LDS cross-wave reduce.
#define FQT 8
__global__ __launch_bounds__(256) void k_feat(
    const float* __restrict__ feat, const float* __restrict__ w1,
    const float* __restrict__ b1, const float* __restrict__ w2,
    const float* __restrict__ b2, float* __restrict__ f1T,
    float* __restrict__ f2) {
  const int t = threadIdx.x;
  const int qi = t & 7, ch = t >> 3;  // 32 chunks of 8 channels
  const int n = blockIdx.y;
  const int c0 = ch * 8;
  const float* fp = feat + ((size_t)n * CIN + c0) * HW + blockIdx.x * FQT + qi;
  float a1[NCL], a2[NCL];
#pragma unroll
  for (int k = 0; k < NCL; ++k) { a1[k] = 0.f; a2[k] = 0.f; }
#pragma unroll
  for (int cc = 0; cc < 8; ++cc) {
    float v = fp[(size_t)cc * HW];
#pragma unroll
    for (int k = 0; k < NCL; ++k) {
      a1[k] = fmaf(v, w1[k * CIN + c0 + cc], a1[k]);
      a2[k] = fmaf(v, w2[k * CIN + c0 + cc], a2[k]);
    }
  }
#pragma unroll
  for (int k = 0; k < NCL; ++k) {
    a1[k] += __shfl_xor(a1[k], 8, 64);
    a2[k] += __shfl_xor(a2[k], 8, 64);
    a1[k] += __shfl_xor(a1[k], 16, 64);
    a2[k] += __shfl_xor(a2[k], 16, 64);
    a1[k] += __shfl_xor(a1[k], 32, 64);
    a2[k] += __shfl_xor(a2[k], 32, 64);
  }
  __shared__ float p1[4][FQT][NCL];
  __shared__ float p2[4][FQT][NCL];
  const int wave = t >> 6, lane = t & 63;
  if (lane < FQT) {
#pragma unroll
    for (int k = 0; k < NCL; ++k) {
      p1[wave][lane][k] = a1[k];
      p2[wave][lane][k] = a2[k];
    }
  }
  __syncthreads();
  const float SCALE = 1.0f / sqrtf(21.0f);
  if (t < FQT * NCL) {
    int qq = t & 7, k = t >> 3;
    float s1 = b1[k] + p1[0][qq][k] + p1[1][qq][k] + p1[2][qq][k] +
               p1[3][qq][k];
    float s2 = b2[k] + p2[0][qq][k] + p2[1][qq][k] + p2[2][qq][k] +
               p2[3][qq][k];
    int qg = blockIdx.x * FQT + qq;
    f1T[((size_t)n * HW + qg) * PADK + k] = s1 * SCALE;  // pre-scaled
    f2[((size_t)n * NCL + k) * HW + qg] = s2;
  }
}

// ---------------------------------------------------------------------------
// Kernel C (v7, k_lpart): l[n][p] = sum_q exp(S) computed in CORR8's
// geometry. R13/R14 ledger: stats4's cost driver was f2-sweep redundancy
// (each of 2048 blocks read the FULL 344 KB f2n -> 688 MB of L2 traffic).
// Here the q-axis is block-split 16 ways like corr8: fq[21] float4 lives in
// registers (f2 read once per q-slice, 10.8 MB total), sf1 staged once, and
// each wave reduces its 4-q exp sums across lanes (6-step shfl butterfly,
// ~8% of the 84-FMA dot cost) into lpart[p]; one float atomicAdd per (p,qb)
// into the zeroed l buffer (131K atomics, trivial). Cliff-insulated: the
// 512-block grid caps residency at 2 waves/SIMD for any VGPR <= 256.
#define PSPLIT 16
#define DPS 256
__global__ __launch_bounds__(256) void k_lpart(
    const float* __restrict__ f1T, const float* __restrict__ f2,
    float* __restrict__ l) {
  __shared__ float sf1[DPS * PADK];  // 24 KB
  __shared__ float lpart[DPS];       // 1 KB
  const int t = threadIdx.x;
  const int lane = t & 63, wid = t >> 6;
  const int n = blockIdx.z, pb = blockIdx.y;
  const int pbase = pb * DPS;
  {
    const float4* gf = (const float4*)(f1T + ((size_t)n * HW + pbase) * PADK);
    float4* sa = (float4*)sf1;
#pragma unroll
    for (int i = 0; i < DPS * (PADK / 4) / 256; ++i)
      sa[t + i * 256] = gf[t + i * 256];
  }
  __syncthreads();
  const int q = blockIdx.x * 256 + lane * 4;
  const float* f2n = f2 + (size_t)n * NCL * HW;
  float4 fq[NCL];
#pragma unroll
  for (int k = 0; k < NCL; ++k)
    fq[k] = *(const float4*)(f2n + (size_t)k * HW + q);
  const int plo = wid * (DPS / 4);
  const int phi = plo + (DPS / 4);
  for (int p = plo; p < phi; ++p) {
    const float4* r1 = (const float4*)(sf1 + p * PADK);
    float a[NCL];
    *(float4*)(a + 0) = r1[0];
    *(float4*)(a + 4) = r1[1];
    *(float4*)(a + 8) = r1[2];
    *(float4*)(a + 12) = r1[3];
    *(float4*)(a + 16) = r1[4];
    a[20] = ((const float*)r1)[20];
    float d0 = 0.f, d1 = 0.f, d2 = 0.f, d3 = 0.f;
#pragma unroll
    for (int k = 0; k < NCL; ++k) {
      d0 = fmaf(a[k], fq[k].x, d0);
      d1 = fmaf(a[k], fq[k].y, d1);
      d2 = fmaf(a[k], fq[k].z, d2);
      d3 = fmaf(a[k], fq[k].w, d3);
    }
    float s = __expf(d0) + __expf(d1) + __expf(d2) + __expf(d3);
#pragma unroll
    for (int off = 32; off > 0; off >>= 1) s += __shfl_xor(s, off, 64);
    if (lane == 0) lpart[p] = s;
  }
  __syncthreads();
  if (t < DPS) atomicAdd(l + (size_t)n * HW + pbase + t, lpart[t]);
}

// ---------------------------------------------------------------------------
// Kernel D (v9, k_corrB): corr8 (R9-proven structural optimum: DPS=256, 512
// blocks = 2 blocks/CU single round) + in-LDS sot build. The otT global
// buffer and its producer are gone: a prologue computes the bilinear
// downsample of `out` times 1/l[p] (from k_lpart) straight into the sot LDS
// tile (21 items/thread, ~3-5 us). VGPR may exceed 128 from the prologue's
// double-precision coords, but corr8's grid only ever used 2 waves/SIMD, so
// the 128-cliff is inert here (residency unchanged for any VGPR <= 256).
__global__ __launch_bounds__(256) void k_corrB(
    const float* __restrict__ f1T, const float* __restrict__ f2,
    const float* __restrict__ out, const float* __restrict__ l,
    float* __restrict__ part) {
  __shared__ float smem[2 * DPS * PADK];  // 48 KB: sf1 | sot
  __shared__ float linv[DPS];             // 1 KB
  float* sf1 = smem;
  float* sot = smem + DPS * PADK;
  const int t = threadIdx.x;  // 0..255
  const int lane = t & 63, wid = t >> 6;
  const int n = blockIdx.z, pb = blockIdx.y;
  const int pbase = pb * DPS;
  {
    const float4* gf = (const float4*)(f1T + ((size_t)n * HW + pbase) * PADK);
    float4* sa = (float4*)sf1;
#pragma unroll
    for (int i = 0; i < DPS * (PADK / 4) / 256; ++i)
      sa[t + i * 256] = gf[t + i * 256];
  }
  if (t < DPS) linv[t] = fastrcp(l[(size_t)n * HW + pbase + t]);
  __syncthreads();
  // sot build: bilinear downsample (128->64, align-corners) x 1/l.
  for (int o = t; o < DPS * NCL; o += 256) {
    int pl = o / NCL, c = o - pl * NCL;
    int pg = pbase + pl;
    int i = pg >> 6, j = pg & 63;
    double sy = (double)i * (127.0 / 63.0);
    double sx = (double)j * (127.0 / 63.0);
    int y0 = (int)sy, x0 = (int)sx;
    float wy = (float)(sy - y0), wx = (float)(sx - x0);
    int y1 = min(y0 + 1, 127), x1 = min(x0 + 1, 127);
    const float* src = out + ((size_t)n * NCL + c) * (128 * 128);
    float v00 = src[y0 * 128 + x0], v10 = src[y1 * 128 + x0];
    float v01 = src[y0 * 128 + x1], v11 = src[y1 * 128 + x1];
    float r0 = v00 * (1.f - wy) + v10 * wy;
    float r1 = v01 * (1.f - wy) + v11 * wy;
    float val = r0 * (1.f - wx) + r1 * wx;
    sot[pl * PADK + c] = val * linv[pl];
  }
  __syncthreads();
  const int q = blockIdx.x * 256 + lane * 4;
  const float* f2n = f2 + (size_t)n * NCL * HW;
  float4 fq[NCL];
#pragma unroll
  for (int k = 0; k < NCL; ++k)
    fq[k] = *(const float4*)(f2n + (size_t)k * HW + q);
  float4 acc[NCL];
#pragma unroll
  for (int k = 0; k < NCL; ++k) acc[k] = make_float4(0.f, 0.f, 0.f, 0.f);
  const int plo = wid * (DPS / 4);
  const int phi = plo + (DPS / 4);
#pragma unroll 2
  for (int p = plo; p < phi; ++p) {
    const float4* r1 = (const float4*)(sf1 + p * PADK);
    float a[NCL];
    *(float4*)(a + 0) = r1[0];
    *(float4*)(a + 4) = r1[1];
    *(float4*)(a + 8) = r1[2];
    *(float4*)(a + 12) = r1[3];
    *(float4*)(a + 16) = r1[4];
    a[20] = ((const float*)r1)[20];
    float d0 = 0.f, d1 = 0.f, d2 = 0.f, d3 = 0.f;  // 4 independent chains
#pragma unroll
    for (int k = 0; k < NCL; ++k) {
      d0 = fmaf(a[k], fq[k].x, d0);
      d1 = fmaf(a[k], fq[k].y, d1);
      d2 = fmaf(a[k], fq[k].z, d2);
      d3 = fmaf(a[k], fq[k].w, d3);
    }
    float w0 = __expf(d0), w1 = __expf(d1), w2 = __expf(d2), w3 = __expf(d3);
    const float4* ro = (const float4*)(sot + p * PADK);
    float o[NCL];
    *(float4*)(o + 0) = ro[0];
    *(float4*)(o + 4) = ro[1];
    *(float4*)(o + 8) = ro[2];
    *(float4*)(o + 12) = ro[3];
    *(float4*)(o + 16) = ro[4];
    o[20] = ((const float*)ro)[20];
#pragma unroll
    for (int k = 0; k < NCL; ++k) {
      acc[k].x = fmaf(o[k], w0, acc[k].x);
      acc[k].y = fmaf(o[k], w1, acc[k].y);
      acc[k].z = fmaf(o[k], w2, acc[k].z);
      acc[k].w = fmaf(o[k], w3, acc[k].w);
    }
  }
  // 3-round ping-pong combine through the (now dead) LDS tile.
  __syncthreads();  // all ds reads of sf1/sot done; safe to reuse smem
  float4* sbuf = (float4*)smem;
  if (wid == 1) {
#pragma unroll
    for (int c = 0; c < NCL; ++c) sbuf[c * 64 + lane] = acc[c];
  }
  __syncthreads();
  if (wid == 0) {
#pragma unroll
    for (int c = 0; c < NCL; ++c) {
      float4 v = sbuf[c * 64 + lane];
      acc[c].x += v.x; acc[c].y += v.y; acc[c].z += v.z; acc[c].w += v.w;
    }
  }
  __syncthreads();
  if (wid == 3) {
#pragma unroll
    for (int c = 0; c < NCL; ++c) sbuf[c * 64 + lane] = acc[c];
  }
  __syncthreads();
  if (wid == 2) {
#pragma unroll
    for (int c = 0; c < NCL; ++c) {
      float4 v = sbuf[c * 64 + lane];
      acc[c].x += v.x; acc[c].y += v.y; acc[c].z += v.z; acc[c].w += v.w;
    }
  }
  __syncthreads();
  if (wid == 2) {
#pragma unroll
    for (int c = 0; c < NCL; ++c) sbuf[c * 64 + lane] = acc[c];
  }
  __syncthreads();
  if (wid == 0) {
    float* po = part + ((size_t)pb * NB + n) * NCL * HW + q;
#pragma unroll
    for (int c = 0; c < NCL; ++c) {
      float4 v = sbuf[c * 64 + lane];
      v.x += acc[c].x; v.y += acc[c].y; v.z += acc[c].z; v.w += acc[c].w;
      *(float4*)(po + (size_t)c * HW) = v;
    }
  }
}

// ---------------------------------------------------------------------------
// Kernel D2 (fallback path only): corr_out = sum over the 16 slabs.
__global__ __launch_bounds__(256) void k_reduce(
    const float* __restrict__ part, float* __restrict__ corr_out) {
  const int idx = blockIdx.x * 256 + threadIdx.x;  // NB*NCL*HW = 672*256
  const float* p = part + idx;
  float s = 0.f;
#pragma unroll
  for (int pb = 0; pb < PSPLIT; ++pb)
    s += p[(size_t)pb * (NB * NCL * HW)];
  corr_out[idx] = s;
}

// ---------------------------------------------------------------------------
// Kernel E body (norm): per sampled row (i, n), 1024 threads (R12-proven:
// 16 waves = 4 waves/SIMD at 1 block/CU).
static __device__ __forceinline__ void norm_body(
    int i, int n, const float* __restrict__ f1T, const float* __restrict__ f2,
    const int* __restrict__ index, float* __restrict__ out0,
    float* row, float* redmn, float* redmx, float* wt, int* it) {
  const int t = threadIdx.x;  // 0..1023
  if (t < 128) {
    double s = (double)t * (63.0 / 127.0);
    int i0 = (int)s;
    wt[t] = (float)(s - i0);
    it[t] = i0;
  }
  int p = index[i];
  p = max(0, min(p, HW - 1));
  const float* f1p = f1T + ((size_t)n * HW + p) * PADK;  // uniform -> s_load
  float a[NCL];
#pragma unroll
  for (int k = 0; k < NCL; ++k) a[k] = f1p[k];
  const float* f2n = f2 + (size_t)n * NCL * HW;
  {
    const int q0 = t * 4;  // 1024 threads x 4 = all 4096 q in one pass
    float d0 = 0.f, d1 = 0.f, d2 = 0.f, d3 = 0.f;
#pragma unroll
    for (int k = 0; k < NCL; ++k) {
      float4 f = *(const float4*)(f2n + (size_t)k * HW + q0);
      d0 = fmaf(a[k], f.x, d0);
      d1 = fmaf(a[k], f.y, d1);
      d2 = fmaf(a[k], f.z, d2);
      d3 = fmaf(a[k], f.w, d3);
    }
    *(float4*)(row + q0) =
        make_float4(__expf(d0), __expf(d1), __expf(d2), __expf(d3));
  }
  __syncthreads();
  float vv[16];
  float lmn = 1e30f, lmx = -1e30f;
#pragma unroll
  for (int j = 0; j < 16; ++j) {
    int pix = t + j * 1024;
    int yy = pix >> 7, xx = pix & 127;
    int y0 = it[yy], x0 = it[xx];
    float wy = wt[yy], wx = wt[xx];
    int y1 = min(y0 + 1, 63), x1 = min(x0 + 1, 63);
    float r0 = row[y0 * 64 + x0] * (1.f - wy) + row[y1 * 64 + x0] * wy;
    float r1 = row[y0 * 64 + x1] * (1.f - wy) + row[y1 * 64 + x1] * wy;
    float v = r0 * (1.f - wx) + r1 * wx;
    vv[j] = v;
    lmn = fminf(lmn, v);
    lmx = fmaxf(lmx, v);
  }
  for (int off = 32; off > 0; off >>= 1) {
    lmn = fminf(lmn, __shfl_xor(lmn, off, 64));
    lmx = fmaxf(lmx, __shfl_xor(lmx, off, 64));
  }
  const int wave = t >> 6, lane = t & 63;
  if (lane == 0) { redmn[wave] = lmn; redmx[wave] = lmx; }
  __syncthreads();
  float mn = redmn[0], mx = redmx[0];
#pragma unroll
  for (int w = 1; w < 16; ++w) {
    mn = fminf(mn, redmn[w]);
    mx = fmaxf(mx, redmx[w]);
  }
  float rng = mx - mn;
  float* slot = out0 + ((size_t)n * 128 + i) * (128 * 128);
#pragma unroll
  for (int j = 0; j < 16; ++j) {
    int pix = t + j * 1024;
    float nrm = (vv[j] - mn) / rng;
    slot[pix] = (nrm > 0.5f) ? 1.0f : 0.0f;
  }
}

// Fused tail (main path): blocks 0..167 do the slab reduce, blocks 168..423
// do norm. Legal in one launch because part lives in ws (NOT aliasing out0).
__global__ __launch_bounds__(1024) void k_tail(
    const float* __restrict__ part, float* __restrict__ corr_out,
    const float* __restrict__ f1T, const float* __restrict__ f2,
    const int* __restrict__ index, float* __restrict__ out0) {
  __shared__ float row[HW];
  __shared__ float redmn[16], redmx[16];
  __shared__ float wt[128];
  __shared__ int it[128];
  const int bx = blockIdx.x;
  if (bx < 168) {
    const int idx = bx * 1024 + threadIdx.x;
    const float* p = part + idx;
    float s = 0.f;
#pragma unroll
    for (int pb = 0; pb < PSPLIT; ++pb)
      s += p[(size_t)pb * (NB * NCL * HW)];
    corr_out[idx] = s;
    return;
  }
  const int nb = bx - 168;
  norm_body(nb & 127, nb >> 7, f1T, f2, index, out0, row, redmn, redmx, wt,
            it);
}

// Fallback norm (part aliases out0; must run after k_reduce).
__global__ __launch_bounds__(1024) void k_norm(
    const float* __restrict__ f1T, const float* __restrict__ f2,
    const int* __restrict__ index, float* __restrict__ out0) {
  __shared__ float row[HW];
  __shared__ float redmn[16], redmx[16];
  __shared__ float wt[128];
  __shared__ int it[128];
  norm_body(blockIdx.x, blockIdx.y, f1T, f2, index, out0, row, redmn, redmx,
            wt, it);
}

// ---------------------------------------------------------------------------
extern "C" void kernel_launch(void* const* d_in, const int* in_sizes, int n_in,
                              void* d_out, int out_size, void* d_ws,
                              size_t ws_size, hipStream_t stream) {
  (void)in_sizes; (void)n_in; (void)out_size;
  const float* feat = (const float*)d_in[0];
  const float* out  = (const float*)d_in[1];
  const float* w1   = (const float*)d_in[2];
  const float* b1   = (const float*)d_in[3];
  const float* w2   = (const float*)d_in[4];
  const float* b2   = (const float*)d_in[5];
  const int* index  = (const int*)d_in[6];

  float* ws   = (float*)d_ws;
  float* f1T  = ws;                                   // 2*4096*24 = 196608
  float* f2   = ws + 196608;                          // 2*21*4096 = 172032
  float* lbuf = ws + 196608 + 172032;                 // 2*4096   = 8192
  const size_t ws_base = 196608 + 172032 + 8192;      // 376832 floats

  float* out0     = (float*)d_out;                    // 2*128*128*128
  float* corr_out = out0 + (size_t)NB * 128 * 128 * 128;  // 2*21*4096

  hipMemsetAsync(lbuf, 0, (size_t)NB * HW * sizeof(float), stream);
  k_feat<<<dim3(HW / FQT, 2), 256, 0, stream>>>(feat, w1, b1, w2, b2, f1T, f2);
  k_lpart<<<dim3(16, PSPLIT, 2), 256, 0, stream>>>(f1T, f2, lbuf);

  // Main path: 16 slabs (10.5 MB) in workspace (R10's counters PROVED the
  // ws path ran with 22 MB of slabs -> ws_size >= 24 MB) + fused tail.
  const size_t need =
      (ws_base + (size_t)PSPLIT * NB * NCL * HW) * sizeof(float);
  if (ws_size >= need) {
    float* part = ws + ws_base;
    k_corrB<<<dim3(16, PSPLIT, 2), 256, 0, stream>>>(f1T, f2, out, lbuf,
                                                     part);
    k_tail<<<dim3(168 + 256), 1024, 0, stream>>>(part, corr_out, f1T, f2,
                                                 index, out0);
  } else {
    // Fallback: slabs parked in out0, separate reduce + norm.
    float* part = out0;
    k_corrB<<<dim3(16, PSPLIT, 2), 256, 0, stream>>>(f1T, f2, out, lbuf,
                                                     part);
    k_reduce<<<dim3(672), 256, 0, stream>>>(part, corr_out);
    k_norm<<<dim3(128, 2), 1024, 0, stream>>>(f1T, f2, index, out0);
  }
}

// Round 16
// 185.105 us; speedup vs baseline: 1.0686x; 1.0686x over previous
//
#include <hip/hip_runtime.h>
#include <math.h>

#define NCL 21
#define CIN 256
#define HW 4096
#define PADK 24
#define NB 2

static __device__ __forceinline__ float fastrcp(float x) {
  return __builtin_amdgcn_rcpf(x);
}

// ---------------------------------------------------------------------------
// Kernel A (v2, R14-proven): f1/f2 = 1x1 conv, f1 pre-scaled by 1/sqrt(21).
// 1024 blocks = 4 blocks/CU; 32 chunks of 8 channels; wave-butterfly +
// small-LDS cross-wave reduce.
#define FQT 8
__global__ __launch_bounds__(256) void k_feat(
    const float* __restrict__ feat, const float* __restrict__ w1,
    const float* __restrict__ b1, const float* __restrict__ w2,
    const float* __restrict__ b2, float* __restrict__ f1T,
    float* __restrict__ f2) {
  const int t = threadIdx.x;
  const int qi = t & 7, ch = t >> 3;  // 32 chunks of 8 channels
  const int n = blockIdx.y;
  const int c0 = ch * 8;
  const float* fp = feat + ((size_t)n * CIN + c0) * HW + blockIdx.x * FQT + qi;
  float a1[NCL], a2[NCL];
#pragma unroll
  for (int k = 0; k < NCL; ++k) { a1[k] = 0.f; a2[k] = 0.f; }
#pragma unroll
  for (int cc = 0; cc < 8; ++cc) {
    float v = fp[(size_t)cc * HW];
#pragma unroll
    for (int k = 0; k < NCL; ++k) {
      a1[k] = fmaf(v, w1[k * CIN + c0 + cc], a1[k]);
      a2[k] = fmaf(v, w2[k * CIN + c0 + cc], a2[k]);
    }
  }
#pragma unroll
  for (int k = 0; k < NCL; ++k) {
    a1[k] += __shfl_xor(a1[k], 8, 64);
    a2[k] += __shfl_xor(a2[k], 8, 64);
    a1[k] += __shfl_xor(a1[k], 16, 64);
    a2[k] += __shfl_xor(a2[k], 16, 64);
    a1[k] += __shfl_xor(a1[k], 32, 64);
    a2[k] += __shfl_xor(a2[k], 32, 64);
  }
  __shared__ float p1[4][FQT][NCL];
  __shared__ float p2[4][FQT][NCL];
  const int wave = t >> 6, lane = t & 63;
  if (lane < FQT) {
#pragma unroll
    for (int k = 0; k < NCL; ++k) {
      p1[wave][lane][k] = a1[k];
      p2[wave][lane][k] = a2[k];
    }
  }
  __syncthreads();
  const float SCALE = 1.0f / sqrtf(21.0f);
  if (t < FQT * NCL) {
    int qq = t & 7, k = t >> 3;
    float s1 = b1[k] + p1[0][qq][k] + p1[1][qq][k] + p1[2][qq][k] +
               p1[3][qq][k];
    float s2 = b2[k] + p2[0][qq][k] + p2[1][qq][k] + p2[2][qq][k] +
               p2[3][qq][k];
    int qg = blockIdx.x * FQT + qq;
    f1T[((size_t)n * HW + qg) * PADK + k] = s1 * SCALE;  // pre-scaled
    f2[((size_t)n * NCL + k) * HW + qg] = s2;
  }
}

// ---------------------------------------------------------------------------
// Kernel C (v7, k_lpart — R15, structure sound): l[n][p] = sum_q exp(S) in
// corr8's geometry. stats4's cost driver was f2-sweep redundancy (2048
// blocks x full 344 KB f2n = 688 MB L2 traffic); here the q-axis is
// block-split 16 ways: fq[21] float4 in registers (f2 read once per
// q-slice, 10.8 MB total), sf1 staged once, 6-step shfl butterfly per
// p-iter, one atomicAdd per (p,qb) into zeroed l (131K atomics, trivial).
#define PSPLIT 16
#define DPS 256
__global__ __launch_bounds__(256) void k_lpart(
    const float* __restrict__ f1T, const float* __restrict__ f2,
    float* __restrict__ l) {
  __shared__ float sf1[DPS * PADK];  // 24 KB
  __shared__ float lpart[DPS];       // 1 KB
  const int t = threadIdx.x;
  const int lane = t & 63, wid = t >> 6;
  const int n = blockIdx.z, pb = blockIdx.y;
  const int pbase = pb * DPS;
  {
    const float4* gf = (const float4*)(f1T + ((size_t)n * HW + pbase) * PADK);
    float4* sa = (float4*)sf1;
#pragma unroll
    for (int i = 0; i < DPS * (PADK / 4) / 256; ++i)
      sa[t + i * 256] = gf[t + i * 256];
  }
  __syncthreads();
  const int q = blockIdx.x * 256 + lane * 4;
  const float* f2n = f2 + (size_t)n * NCL * HW;
  float4 fq[NCL];
#pragma unroll
  for (int k = 0; k < NCL; ++k)
    fq[k] = *(const float4*)(f2n + (size_t)k * HW + q);
  const int plo = wid * (DPS / 4);
  const int phi = plo + (DPS / 4);
  for (int p = plo; p < phi; ++p) {
    const float4* r1 = (const float4*)(sf1 + p * PADK);
    float a[NCL];
    *(float4*)(a + 0) = r1[0];
    *(float4*)(a + 4) = r1[1];
    *(float4*)(a + 8) = r1[2];
    *(float4*)(a + 12) = r1[3];
    *(float4*)(a + 16) = r1[4];
    a[20] = ((const float*)r1)[20];
    float d0 = 0.f, d1 = 0.f, d2 = 0.f, d3 = 0.f;
#pragma unroll
    for (int k = 0; k < NCL; ++k) {
      d0 = fmaf(a[k], fq[k].x, d0);
      d1 = fmaf(a[k], fq[k].y, d1);
      d2 = fmaf(a[k], fq[k].z, d2);
      d3 = fmaf(a[k], fq[k].w, d3);
    }
    float s = __expf(d0) + __expf(d1) + __expf(d2) + __expf(d3);
#pragma unroll
    for (int off = 32; off > 0; off >>= 1) s += __shfl_xor(s, off, 64);
    if (lane == 0) lpart[p] = s;
  }
  __syncthreads();
  if (t < DPS) atomicAdd(l + (size_t)n * HW + pbase + t, lpart[t]);
}

// ---------------------------------------------------------------------------
// Kernel B (k_outr, standalone — R2-proven ~4 us, restored): bilinear
// downsample of out (128->64, align-corners) times 1/l, stored transposed+
// padded otT[n][p][24]. R15 lesson: fusing this gather into corrB's LDS
// prologue cost +16 us (uncoalesced out reads doubled FETCH, 86K bank
// conflicts, serialized prologue); as a standalone bulk kernel it's ~4 us
// and corr8 stays at its 46 us optimum.
__global__ __launch_bounds__(256) void k_outr(
    const float* __restrict__ out, const float* __restrict__ l,
    float* __restrict__ otT) {
  int idx = blockIdx.x * 256 + threadIdx.x;
  if (idx >= NB * NCL * HW) return;
  int p = idx & (HW - 1);
  int nk = idx >> 12;
  int i = p >> 6, j = p & 63;
  double sy = (double)i * (127.0 / 63.0);
  double sx = (double)j * (127.0 / 63.0);
  int y0 = (int)sy, x0 = (int)sx;
  float wy = (float)(sy - y0), wx = (float)(sx - x0);
  int y1 = min(y0 + 1, 127), x1 = min(x0 + 1, 127);
  const float* src = out + (size_t)nk * (128 * 128);
  float v00 = src[y0 * 128 + x0], v10 = src[y1 * 128 + x0];
  float v01 = src[y0 * 128 + x1], v11 = src[y1 * 128 + x1];
  float r0 = v00 * (1.f - wy) + v10 * wy;
  float r1 = v01 * (1.f - wy) + v11 * wy;
  float val = r0 * (1.f - wx) + r1 * wx;
  int n = nk / NCL, c = nk % NCL;
  val *= fastrcp(l[(size_t)n * HW + p]);
  otT[((size_t)n * HW + p) * PADK + c] = val;
}

// ---------------------------------------------------------------------------
// Kernel D (v8, R9-proven, bit-exact): DPS=256 / 512 blocks = 2 blocks/CU
// single round. The Q=4 loop's true live set is ~168 unified regs (arch
// VGPR 128 + AGPR balance) -> real cap ~3 waves/SIMD; finer p-splits leave
// ragged rounds. Structural optimum of this decomposition.
__global__ __launch_bounds__(256) void k_corr8(
    const float* __restrict__ f1T, const float* __restrict__ f2,
    const float* __restrict__ otT, float* __restrict__ part) {
  __shared__ float smem[2 * DPS * PADK];  // 48 KB: sf1 | sot
  float* sf1 = smem;
  float* sot = smem + DPS * PADK;
  const int t = threadIdx.x;  // 0..255
  const int lane = t & 63, wid = t >> 6;
  const int n = blockIdx.z, pb = blockIdx.y;
  const int pbase = pb * DPS;
  {
    const float4* gf = (const float4*)(f1T + ((size_t)n * HW + pbase) * PADK);
    const float4* go = (const float4*)(otT + ((size_t)n * HW + pbase) * PADK);
    float4* sa = (float4*)sf1;
    float4* sb = (float4*)sot;
#pragma unroll
    for (int i = 0; i < DPS * (PADK / 4) / 256; ++i) {
      sa[t + i * 256] = gf[t + i * 256];
      sb[t + i * 256] = go[t + i * 256];
    }
  }
  __syncthreads();
  const int q = blockIdx.x * 256 + lane * 4;
  const float* f2n = f2 + (size_t)n * NCL * HW;
  float4 fq[NCL];
#pragma unroll
  for (int k = 0; k < NCL; ++k)
    fq[k] = *(const float4*)(f2n + (size_t)k * HW + q);
  float4 acc[NCL];
#pragma unroll
  for (int k = 0; k < NCL; ++k) acc[k] = make_float4(0.f, 0.f, 0.f, 0.f);
  const int plo = wid * (DPS / 4);
  const int phi = plo + (DPS / 4);
#pragma unroll 2
  for (int p = plo; p < phi; ++p) {
    const float4* r1 = (const float4*)(sf1 + p * PADK);
    float a[NCL];
    *(float4*)(a + 0) = r1[0];
    *(float4*)(a + 4) = r1[1];
    *(float4*)(a + 8) = r1[2];
    *(float4*)(a + 12) = r1[3];
    *(float4*)(a + 16) = r1[4];
    a[20] = ((const float*)r1)[20];
    float d0 = 0.f, d1 = 0.f, d2 = 0.f, d3 = 0.f;  // 4 independent chains
#pragma unroll
    for (int k = 0; k < NCL; ++k) {
      d0 = fmaf(a[k], fq[k].x, d0);
      d1 = fmaf(a[k], fq[k].y, d1);
      d2 = fmaf(a[k], fq[k].z, d2);
      d3 = fmaf(a[k], fq[k].w, d3);
    }
    float w0 = __expf(d0), w1 = __expf(d1), w2 = __expf(d2), w3 = __expf(d3);
    const float4* ro = (const float4*)(sot + p * PADK);
    float o[NCL];
    *(float4*)(o + 0) = ro[0];
    *(float4*)(o + 4) = ro[1];
    *(float4*)(o + 8) = ro[2];
    *(float4*)(o + 12) = ro[3];
    *(float4*)(o + 16) = ro[4];
    o[20] = ((const float*)ro)[20];
#pragma unroll
    for (int k = 0; k < NCL; ++k) {
      acc[k].x = fmaf(o[k], w0, acc[k].x);
      acc[k].y = fmaf(o[k], w1, acc[k].y);
      acc[k].z = fmaf(o[k], w2, acc[k].z);
      acc[k].w = fmaf(o[k], w3, acc[k].w);
    }
  }
  // 3-round ping-pong combine through the (now dead) LDS tile.
  __syncthreads();  // all ds reads of sf1/sot done; safe to reuse smem
  float4* sbuf = (float4*)smem;
  if (wid == 1) {
#pragma unroll
    for (int c = 0; c < NCL; ++c) sbuf[c * 64 + lane] = acc[c];
  }
  __syncthreads();
  if (wid == 0) {
#pragma unroll
    for (int c = 0; c < NCL; ++c) {
      float4 v = sbuf[c * 64 + lane];
      acc[c].x += v.x; acc[c].y += v.y; acc[c].z += v.z; acc[c].w += v.w;
    }
  }
  __syncthreads();
  if (wid == 3) {
#pragma unroll
    for (int c = 0; c < NCL; ++c) sbuf[c * 64 + lane] = acc[c];
  }
  __syncthreads();
  if (wid == 2) {
#pragma unroll
    for (int c = 0; c < NCL; ++c) {
      float4 v = sbuf[c * 64 + lane];
      acc[c].x += v.x; acc[c].y += v.y; acc[c].z += v.z; acc[c].w += v.w;
    }
  }
  __syncthreads();
  if (wid == 2) {
#pragma unroll
    for (int c = 0; c < NCL; ++c) sbuf[c * 64 + lane] = acc[c];
  }
  __syncthreads();
  if (wid == 0) {
    float* po = part + ((size_t)pb * NB + n) * NCL * HW + q;
#pragma unroll
    for (int c = 0; c < NCL; ++c) {
      float4 v = sbuf[c * 64 + lane];
      v.x += acc[c].x; v.y += acc[c].y; v.z += acc[c].z; v.w += acc[c].w;
      *(float4*)(po + (size_t)c * HW) = v;
    }
  }
}

// ---------------------------------------------------------------------------
// Kernel D2 (fallback path only): corr_out = sum over the 16 slabs.
__global__ __launch_bounds__(256) void k_reduce(
    const float* __restrict__ part, float* __restrict__ corr_out) {
  const int idx = blockIdx.x * 256 + threadIdx.x;  // NB*NCL*HW = 672*256
  const float* p = part + idx;
  float s = 0.f;
#pragma unroll
  for (int pb = 0; pb < PSPLIT; ++pb)
    s += p[(size_t)pb * (NB * NCL * HW)];
  corr_out[idx] = s;
}

// ---------------------------------------------------------------------------
// Kernel E body (norm): per sampled row (i, n), 1024 threads (R12-proven:
// 16 waves = 4 waves/SIMD at 1 block/CU).
static __device__ __forceinline__ void norm_body(
    int i, int n, const float* __restrict__ f1T, const float* __restrict__ f2,
    const int* __restrict__ index, float* __restrict__ out0,
    float* row, float* redmn, float* redmx, float* wt, int* it) {
  const int t = threadIdx.x;  // 0..1023
  if (t < 128) {
    double s = (double)t * (63.0 / 127.0);
    int i0 = (int)s;
    wt[t] = (float)(s - i0);
    it[t] = i0;
  }
  int p = index[i];
  p = max(0, min(p, HW - 1));
  const float* f1p = f1T + ((size_t)n * HW + p) * PADK;  // uniform -> s_load
  float a[NCL];
#pragma unroll
  for (int k = 0; k < NCL; ++k) a[k] = f1p[k];
  const float* f2n = f2 + (size_t)n * NCL * HW;
  {
    const int q0 = t * 4;  // 1024 threads x 4 = all 4096 q in one pass
    float d0 = 0.f, d1 = 0.f, d2 = 0.f, d3 = 0.f;
#pragma unroll
    for (int k = 0; k < NCL; ++k) {
      float4 f = *(const float4*)(f2n + (size_t)k * HW + q0);
      d0 = fmaf(a[k], f.x, d0);
      d1 = fmaf(a[k], f.y, d1);
      d2 = fmaf(a[k], f.z, d2);
      d3 = fmaf(a[k], f.w, d3);
    }
    *(float4*)(row + q0) =
        make_float4(__expf(d0), __expf(d1), __expf(d2), __expf(d3));
  }
  __syncthreads();
  float vv[16];
  float lmn = 1e30f, lmx = -1e30f;
#pragma unroll
  for (int j = 0; j < 16; ++j) {
    int pix = t + j * 1024;
    int yy = pix >> 7, xx = pix & 127;
    int y0 = it[yy], x0 = it[xx];
    float wy = wt[yy], wx = wt[xx];
    int y1 = min(y0 + 1, 63), x1 = min(x0 + 1, 63);
    float r0 = row[y0 * 64 + x0] * (1.f - wy) + row[y1 * 64 + x0] * wy;
    float r1 = row[y0 * 64 + x1] * (1.f - wy) + row[y1 * 64 + x1] * wy;
    float v = r0 * (1.f - wx) + r1 * wx;
    vv[j] = v;
    lmn = fminf(lmn, v);
    lmx = fmaxf(lmx, v);
  }
  for (int off = 32; off > 0; off >>= 1) {
    lmn = fminf(lmn, __shfl_xor(lmn, off, 64));
    lmx = fmaxf(lmx, __shfl_xor(lmx, off, 64));
  }
  const int wave = t >> 6, lane = t & 63;
  if (lane == 0) { redmn[wave] = lmn; redmx[wave] = lmx; }
  __syncthreads();
  float mn = redmn[0], mx = redmx[0];
#pragma unroll
  for (int w = 1; w < 16; ++w) {
    mn = fminf(mn, redmn[w]);
    mx = fmaxf(mx, redmx[w]);
  }
  float rng = mx - mn;
  float* slot = out0 + ((size_t)n * 128 + i) * (128 * 128);
#pragma unroll
  for (int j = 0; j < 16; ++j) {
    int pix = t + j * 1024;
    float nrm = (vv[j] - mn) / rng;
    slot[pix] = (nrm > 0.5f) ? 1.0f : 0.0f;
  }
}

// Fused tail (main path): blocks 0..167 do the slab reduce, blocks 168..423
// do norm. Legal in one launch because part lives in ws (NOT aliasing out0).
__global__ __launch_bounds__(1024) void k_tail(
    const float* __restrict__ part, float* __restrict__ corr_out,
    const float* __restrict__ f1T, const float* __restrict__ f2,
    const int* __restrict__ index, float* __restrict__ out0) {
  __shared__ float row[HW];
  __shared__ float redmn[16], redmx[16];
  __shared__ float wt[128];
  __shared__ int it[128];
  const int bx = blockIdx.x;
  if (bx < 168) {
    const int idx = bx * 1024 + threadIdx.x;
    const float* p = part + idx;
    float s = 0.f;
#pragma unroll
    for (int pb = 0; pb < PSPLIT; ++pb)
      s += p[(size_t)pb * (NB * NCL * HW)];
    corr_out[idx] = s;
    return;
  }
  const int nb = bx - 168;
  norm_body(nb & 127, nb >> 7, f1T, f2, index, out0, row, redmn, redmx, wt,
            it);
}

// Fallback norm (part aliases out0; must run after k_reduce).
__global__ __launch_bounds__(1024) void k_norm(
    const float* __restrict__ f1T, const float* __restrict__ f2,
    const int* __restrict__ index, float* __restrict__ out0) {
  __shared__ float row[HW];
  __shared__ float redmn[16], redmx[16];
  __shared__ float wt[128];
  __shared__ int it[128];
  norm_body(blockIdx.x, blockIdx.y, f1T, f2, index, out0, row, redmn, redmx,
            wt, it);
}

// ---------------------------------------------------------------------------
extern "C" void kernel_launch(void* const* d_in, const int* in_sizes, int n_in,
                              void* d_out, int out_size, void* d_ws,
                              size_t ws_size, hipStream_t stream) {
  (void)in_sizes; (void)n_in; (void)out_size;
  const float* feat = (const float*)d_in[0];
  const float* out  = (const float*)d_in[1];
  const float* w1   = (const float*)d_in[2];
  const float* b1   = (const float*)d_in[3];
  const float* w2   = (const float*)d_in[4];
  const float* b2   = (const float*)d_in[5];
  const int* index  = (const int*)d_in[6];

  float* ws   = (float*)d_ws;
  float* f1T  = ws;                                   // 2*4096*24 = 196608
  float* f2   = ws + 196608;                          // 2*21*4096 = 172032
  float* otT  = ws + 196608 + 172032;                 // 196608
  float* lbuf = ws + 196608 + 172032 + 196608;        // 8192
  const size_t ws_base = 196608 + 172032 + 196608 + 8192;  // 573440 floats

  float* out0     = (float*)d_out;                    // 2*128*128*128
  float* corr_out = out0 + (size_t)NB * 128 * 128 * 128;  // 2*21*4096

  hipMemsetAsync(lbuf, 0, (size_t)NB * HW * sizeof(float), stream);
  k_feat<<<dim3(HW / FQT, 2), 256, 0, stream>>>(feat, w1, b1, w2, b2, f1T, f2);
  k_lpart<<<dim3(16, PSPLIT, 2), 256, 0, stream>>>(f1T, f2, lbuf);
  k_outr<<<dim3(672), 256, 0, stream>>>(out, lbuf, otT);

  // Main path: 16 slabs (10.5 MB) in workspace (R10's counters proved
  // ws_size >= 24 MB) + fused tail.
  const size_t need =
      (ws_base + (size_t)PSPLIT * NB * NCL * HW) * sizeof(float);
  if (ws_size >= need) {
    float* part = ws + ws_base;
    k_corr8<<<dim3(16, PSPLIT, 2), 256, 0, stream>>>(f1T, f2, otT, part);
    k_tail<<<dim3(168 + 256), 1024, 0, stream>>>(part, corr_out, f1T, f2,
                                                 index, out0);
  } else {
    // Fallback: slabs parked in out0, separate reduce + norm.
    float* part = out0;
    k_corr8<<<dim3(16, PSPLIT, 2), 256, 0, stream>>>(f1T, f2, otT, part);
    k_reduce<<<dim3(672), 256, 0, stream>>>(part, corr_out);
    k_norm<<<dim3(128, 2), 1024, 0, stream>>>(f1T, f2, index, out0);
  }
}

// Round 17
// 183.666 us; speedup vs baseline: 1.0769x; 1.0078x over previous
//
#include <hip/hip_runtime.h>
#include <math.h>

#define NCL 21
#define CIN 256
#define HW 4096
#define PADK 24
#define NB 2

static __device__ __forceinline__ float fastrcp(float x) {
  return __builtin_amdgcn_rcpf(x);
}

// ---------------------------------------------------------------------------
// Kernel A (v2, R14): f1/f2 = 1x1 conv, f1 pre-scaled by 1/sqrt(21).
// 1024 blocks = 4 blocks/CU (vs v1's 512 = 2); 32 chunks of 8 channels ->
// per-thread s_load+FMA chain halves (336 vs 672); wave-butterfly + 5.4 KB
// LDS cross-wave reduce (v1's 43 KB would cap residency). THIS ROUND is the
// single-variable test of v2 against R12's best-raw config (175.5 us).
#define FQT 8
__global__ __launch_bounds__(256) void k_feat(
    const float* __restrict__ feat, const float* __restrict__ w1,
    const float* __restrict__ b1, const float* __restrict__ w2,
    const float* __restrict__ b2, float* __restrict__ f1T,
    float* __restrict__ f2) {
  const int t = threadIdx.x;
  const int qi = t & 7, ch = t >> 3;  // 32 chunks of 8 channels
  const int n = blockIdx.y;
  const int c0 = ch * 8;
  const float* fp = feat + ((size_t)n * CIN + c0) * HW + blockIdx.x * FQT + qi;
  float a1[NCL], a2[NCL];
#pragma unroll
  for (int k = 0; k < NCL; ++k) { a1[k] = 0.f; a2[k] = 0.f; }
#pragma unroll
  for (int cc = 0; cc < 8; ++cc) {
    float v = fp[(size_t)cc * HW];
#pragma unroll
    for (int k = 0; k < NCL; ++k) {
      a1[k] = fmaf(v, w1[k * CIN + c0 + cc], a1[k]);
      a2[k] = fmaf(v, w2[k * CIN + c0 + cc], a2[k]);
    }
  }
#pragma unroll
  for (int k = 0; k < NCL; ++k) {
    a1[k] += __shfl_xor(a1[k], 8, 64);
    a2[k] += __shfl_xor(a2[k], 8, 64);
    a1[k] += __shfl_xor(a1[k], 16, 64);
    a2[k] += __shfl_xor(a2[k], 16, 64);
    a1[k] += __shfl_xor(a1[k], 32, 64);
    a2[k] += __shfl_xor(a2[k], 32, 64);
  }
  __shared__ float p1[4][FQT][NCL];
  __shared__ float p2[4][FQT][NCL];
  const int wave = t >> 6, lane = t & 63;
  if (lane < FQT) {
#pragma unroll
    for (int k = 0; k < NCL; ++k) {
      p1[wave][lane][k] = a1[k];
      p2[wave][lane][k] = a2[k];
    }
  }
  __syncthreads();
  const float SCALE = 1.0f / sqrtf(21.0f);
  if (t < FQT * NCL) {
    int qq = t & 7, k = t >> 3;
    float s1 = b1[k] + p1[0][qq][k] + p1[1][qq][k] + p1[2][qq][k] +
               p1[3][qq][k];
    float s2 = b2[k] + p2[0][qq][k] + p2[1][qq][k] + p2[2][qq][k] +
               p2[3][qq][k];
    int qg = blockIdx.x * FQT + qq;
    f1T[((size_t)n * HW + qg) * PADK + k] = s1 * SCALE;  // pre-scaled
    f2[((size_t)n * NCL + k) * HW + qg] = s2;
  }
}

// ---------------------------------------------------------------------------
// Kernel C (v4, R12-proven, bit-exact): per block = (8 p-rows, n), all 4096
// q in-block, then the k_outr epilogue for the same 8 p. q=2 (float2) is the
// only PT=8 variant that fits VGPR <= 128 (R7/R8/R10/R11: all q=4 variants
// hit the >128 cliff).
#define PT 8
__global__ __launch_bounds__(256) void k_statsoutr(
    const float* __restrict__ f1T, const float* __restrict__ f2,
    const float* __restrict__ out, float* __restrict__ otT) {
  __shared__ float srow[PT * PADK];  // 8 rows * 24 floats = 768 B
  __shared__ float red[4][PT];
  __shared__ float linv[PT];
  const int t = threadIdx.x;
  const int n = blockIdx.y;
  const int pbase = blockIdx.x * PT;
  if (t < PT * PADK / 4) {
    ((float4*)srow)[t] =
        ((const float4*)(f1T + ((size_t)n * HW + pbase) * PADK))[t];
  }
  __syncthreads();
  const float* f2n = f2 + (size_t)n * NCL * HW;
  float sums[PT];
#pragma unroll
  for (int p = 0; p < PT; ++p) sums[p] = 0.f;
  for (int qc = 0; qc < 8; ++qc) {
    const int q0 = qc * 512 + t * 2;
    float2 dp[PT];  // dot partials: 16 VGPR
#pragma unroll
    for (int p = 0; p < PT; ++p) dp[p] = make_float2(0.f, 0.f);
#pragma unroll
    for (int g = 0; g < 5; ++g) {  // k = 4g .. 4g+3
      float2 fg0 = *(const float2*)(f2n + (size_t)(4 * g + 0) * HW + q0);
      float2 fg1 = *(const float2*)(f2n + (size_t)(4 * g + 1) * HW + q0);
      float2 fg2 = *(const float2*)(f2n + (size_t)(4 * g + 2) * HW + q0);
      float2 fg3 = *(const float2*)(f2n + (size_t)(4 * g + 3) * HW + q0);
#pragma unroll
      for (int p = 0; p < PT; ++p) {
        float4 ag = *(const float4*)(srow + p * PADK + 4 * g);
        dp[p].x = fmaf(ag.x, fg0.x, dp[p].x);
        dp[p].y = fmaf(ag.x, fg0.y, dp[p].y);
        dp[p].x = fmaf(ag.y, fg1.x, dp[p].x);
        dp[p].y = fmaf(ag.y, fg1.y, dp[p].y);
        dp[p].x = fmaf(ag.z, fg2.x, dp[p].x);
        dp[p].y = fmaf(ag.z, fg2.y, dp[p].y);
        dp[p].x = fmaf(ag.w, fg3.x, dp[p].x);
        dp[p].y = fmaf(ag.w, fg3.y, dp[p].y);
      }
    }
    {  // k = 20 tail
      float2 f20 = *(const float2*)(f2n + (size_t)20 * HW + q0);
#pragma unroll
      for (int p = 0; p < PT; ++p) {
        float a20 = srow[p * PADK + 20];
        dp[p].x = fmaf(a20, f20.x, dp[p].x);
        dp[p].y = fmaf(a20, f20.y, dp[p].y);
      }
    }
#pragma unroll
    for (int p = 0; p < PT; ++p)
      sums[p] += __expf(dp[p].x) + __expf(dp[p].y);
  }
  const int wave = t >> 6, lane = t & 63;
#pragma unroll
  for (int p = 0; p < PT; ++p) {
    float s = sums[p];
    for (int off = 32; off > 0; off >>= 1) s += __shfl_xor(s, off, 64);
    if (lane == 0) red[wave][p] = s;
  }
  __syncthreads();
  if (t < PT) {
    float tot = red[0][t] + red[1][t] + red[2][t] + red[3][t];
    linv[t] = fastrcp(tot);
  }
  __syncthreads();
  // k_outr epilogue for the 8 p of this block: 8*21 = 168 outputs.
  for (int o = t; o < PT * NCL; o += 256) {
    int pl = o & 7, c = o >> 3;
    int pg = pbase + pl;
    int i = pg >> 6, j = pg & 63;
    double sy = (double)i * (127.0 / 63.0);
    double sx = (double)j * (127.0 / 63.0);
    int y0 = (int)sy, x0 = (int)sx;
    float wy = (float)(sy - y0), wx = (float)(sx - x0);
    int y1 = min(y0 + 1, 127), x1 = min(x0 + 1, 127);
    const float* src = out + ((size_t)n * NCL + c) * (128 * 128);
    float v00 = src[y0 * 128 + x0], v10 = src[y1 * 128 + x0];
    float v01 = src[y0 * 128 + x1], v11 = src[y1 * 128 + x1];
    float r0 = v00 * (1.f - wy) + v10 * wy;
    float r1 = v01 * (1.f - wy) + v11 * wy;
    float val = r0 * (1.f - wx) + r1 * wx;
    otT[((size_t)n * HW + pg) * PADK + c] = val * linv[pl];
  }
}

// ---------------------------------------------------------------------------
// Kernel D (v8, R9-proven, bit-exact): DPS=256 / 512 blocks = 2 blocks/CU
// single round. Closed-form this round: 12 broadcast-ds issues per p-iter =
// ~25.6 us/CU LDS-issue + ~20 us VALU, SERIALIZED (ds feeds FMA directly; 2
// waves/SIMD can't overlap) = the measured 46. Q=8 would halve ds but needs
// >256 VGPR; more waves are LDS-capped. Structural optimum.
#define PSPLIT 16
#define DPS 256
__global__ __launch_bounds__(256) void k_corr8(
    const float* __restrict__ f1T, const float* __restrict__ f2,
    const float* __restrict__ otT, float* __restrict__ part) {
  __shared__ float smem[2 * DPS * PADK];  // 48 KB: sf1 | sot
  float* sf1 = smem;
  float* sot = smem + DPS * PADK;
  const int t = threadIdx.x;  // 0..255
  const int lane = t & 63, wid = t >> 6;
  const int n = blockIdx.z, pb = blockIdx.y;
  const int pbase = pb * DPS;
  {
    const float4* gf = (const float4*)(f1T + ((size_t)n * HW + pbase) * PADK);
    const float4* go = (const float4*)(otT + ((size_t)n * HW + pbase) * PADK);
    float4* sa = (float4*)sf1;
    float4* sb = (float4*)sot;
#pragma unroll
    for (int i = 0; i < DPS * (PADK / 4) / 256; ++i) {
      sa[t + i * 256] = gf[t + i * 256];
      sb[t + i * 256] = go[t + i * 256];
    }
  }
  __syncthreads();
  const int q = blockIdx.x * 256 + lane * 4;
  const float* f2n = f2 + (size_t)n * NCL * HW;
  float4 fq[NCL];
#pragma unroll
  for (int k = 0; k < NCL; ++k)
    fq[k] = *(const float4*)(f2n + (size_t)k * HW + q);
  float4 acc[NCL];
#pragma unroll
  for (int k = 0; k < NCL; ++k) acc[k] = make_float4(0.f, 0.f, 0.f, 0.f);
  const int plo = wid * (DPS / 4);
  const int phi = plo + (DPS / 4);
#pragma unroll 2
  for (int p = plo; p < phi; ++p) {
    const float4* r1 = (const float4*)(sf1 + p * PADK);
    float a[NCL];
    *(float4*)(a + 0) = r1[0];
    *(float4*)(a + 4) = r1[1];
    *(float4*)(a + 8) = r1[2];
    *(float4*)(a + 12) = r1[3];
    *(float4*)(a + 16) = r1[4];
    a[20] = ((const float*)r1)[20];
    float d0 = 0.f, d1 = 0.f, d2 = 0.f, d3 = 0.f;  // 4 independent chains
#pragma unroll
    for (int k = 0; k < NCL; ++k) {
      d0 = fmaf(a[k], fq[k].x, d0);
      d1 = fmaf(a[k], fq[k].y, d1);
      d2 = fmaf(a[k], fq[k].z, d2);
      d3 = fmaf(a[k], fq[k].w, d3);
    }
    float w0 = __expf(d0), w1 = __expf(d1), w2 = __expf(d2), w3 = __expf(d3);
    const float4* ro = (const float4*)(sot + p * PADK);
    float o[NCL];
    *(float4*)(o + 0) = ro[0];
    *(float4*)(o + 4) = ro[1];
    *(float4*)(o + 8) = ro[2];
    *(float4*)(o + 12) = ro[3];
    *(float4*)(o + 16) = ro[4];
    o[20] = ((const float*)ro)[20];
#pragma unroll
    for (int k = 0; k < NCL; ++k) {
      acc[k].x = fmaf(o[k], w0, acc[k].x);
      acc[k].y = fmaf(o[k], w1, acc[k].y);
      acc[k].z = fmaf(o[k], w2, acc[k].z);
      acc[k].w = fmaf(o[k], w3, acc[k].w);
    }
  }
  // 3-round ping-pong combine through the (now dead) LDS tile.
  __syncthreads();  // all ds reads of sf1/sot done; safe to reuse smem
  float4* sbuf = (float4*)smem;
  if (wid == 1) {
#pragma unroll
    for (int c = 0; c < NCL; ++c) sbuf[c * 64 + lane] = acc[c];
  }
  __syncthreads();
  if (wid == 0) {
#pragma unroll
    for (int c = 0; c < NCL; ++c) {
      float4 v = sbuf[c * 64 + lane];
      acc[c].x += v.x; acc[c].y += v.y; acc[c].z += v.z; acc[c].w += v.w;
    }
  }
  __syncthreads();
  if (wid == 3) {
#pragma unroll
    for (int c = 0; c < NCL; ++c) sbuf[c * 64 + lane] = acc[c];
  }
  __syncthreads();
  if (wid == 2) {
#pragma unroll
    for (int c = 0; c < NCL; ++c) {
      float4 v = sbuf[c * 64 + lane];
      acc[c].x += v.x; acc[c].y += v.y; acc[c].z += v.z; acc[c].w += v.w;
    }
  }
  __syncthreads();
  if (wid == 2) {
#pragma unroll
    for (int c = 0; c < NCL; ++c) sbuf[c * 64 + lane] = acc[c];
  }
  __syncthreads();
  if (wid == 0) {
    float* po = part + ((size_t)pb * NB + n) * NCL * HW + q;
#pragma unroll
    for (int c = 0; c < NCL; ++c) {
      float4 v = sbuf[c * 64 + lane];
      v.x += acc[c].x; v.y += acc[c].y; v.z += acc[c].z; v.w += acc[c].w;
      *(float4*)(po + (size_t)c * HW) = v;
    }
  }
}

// ---------------------------------------------------------------------------
// Kernel D2 (R12-proven): corr_out = sum over the 16 slabs. 672 blocks.
__global__ __launch_bounds__(256) void k_reduce(
    const float* __restrict__ part, float* __restrict__ corr_out) {
  const int idx = blockIdx.x * 256 + threadIdx.x;  // NB*NCL*HW = 672*256
  const float* p = part + idx;
  float s = 0.f;
#pragma unroll
  for (int pb = 0; pb < PSPLIT; ++pb)
    s += p[(size_t)pb * (NB * NCL * HW)];
  corr_out[idx] = s;
}

// ---------------------------------------------------------------------------
// Kernel E (R12-proven): per sampled row (i, n), 1024 threads (16 waves =
// 4 waves/SIMD at 1 block/CU). Row compute in one pass, upsample 16 px/
// thread, min/max over 16 waves, booleans out. Runs after k_reduce (slabs
// alias out0).
__global__ __launch_bounds__(1024) void k_norm(
    const float* __restrict__ f1T, const float* __restrict__ f2,
    const int* __restrict__ index, float* __restrict__ out0) {
  __shared__ float row[HW];
  __shared__ float redmn[16], redmx[16];
  __shared__ float wt[128];
  __shared__ int it[128];
  const int t = threadIdx.x;  // 0..1023
  const int i = blockIdx.x;
  const int n = blockIdx.y;
  if (t < 128) {
    double s = (double)t * (63.0 / 127.0);
    int i0 = (int)s;
    wt[t] = (float)(s - i0);
    it[t] = i0;
  }
  int p = index[i];
  p = max(0, min(p, HW - 1));
  const float* f1p = f1T + ((size_t)n * HW + p) * PADK;  // uniform -> s_load
  float a[NCL];
#pragma unroll
  for (int k = 0; k < NCL; ++k) a[k] = f1p[k];
  const float* f2n = f2 + (size_t)n * NCL * HW;
  {
    const int q0 = t * 4;  // 1024 threads x 4 = all 4096 q in one pass
    float d0 = 0.f, d1 = 0.f, d2 = 0.f, d3 = 0.f;
#pragma unroll
    for (int k = 0; k < NCL; ++k) {
      float4 f = *(const float4*)(f2n + (size_t)k * HW + q0);
      d0 = fmaf(a[k], f.x, d0);
      d1 = fmaf(a[k], f.y, d1);
      d2 = fmaf(a[k], f.z, d2);
      d3 = fmaf(a[k], f.w, d3);
    }
    *(float4*)(row + q0) =
        make_float4(__expf(d0), __expf(d1), __expf(d2), __expf(d3));
  }
  __syncthreads();
  float vv[16];
  float lmn = 1e30f, lmx = -1e30f;
#pragma unroll
  for (int j = 0; j < 16; ++j) {
    int pix = t + j * 1024;
    int yy = pix >> 7, xx = pix & 127;
    int y0 = it[yy], x0 = it[xx];
    float wy = wt[yy], wx = wt[xx];
    int y1 = min(y0 + 1, 63), x1 = min(x0 + 1, 63);
    float r0 = row[y0 * 64 + x0] * (1.f - wy) + row[y1 * 64 + x0] * wy;
    float r1 = row[y0 * 64 + x1] * (1.f - wy) + row[y1 * 64 + x1] * wy;
    float v = r0 * (1.f - wx) + r1 * wx;
    vv[j] = v;
    lmn = fminf(lmn, v);
    lmx = fmaxf(lmx, v);
  }
  for (int off = 32; off > 0; off >>= 1) {
    lmn = fminf(lmn, __shfl_xor(lmn, off, 64));
    lmx = fmaxf(lmx, __shfl_xor(lmx, off, 64));
  }
  const int wave = t >> 6, lane = t & 63;
  if (lane == 0) { redmn[wave] = lmn; redmx[wave] = lmx; }
  __syncthreads();
  float mn = redmn[0], mx = redmx[0];
#pragma unroll
  for (int w = 1; w < 16; ++w) {
    mn = fminf(mn, redmn[w]);
    mx = fmaxf(mx, redmx[w]);
  }
  float rng = mx - mn;
  float* slot = out0 + ((size_t)n * 128 + i) * (128 * 128);
#pragma unroll
  for (int j = 0; j < 16; ++j) {
    int pix = t + j * 1024;
    float nrm = (vv[j] - mn) / rng;
    slot[pix] = (nrm > 0.5f) ? 1.0f : 0.0f;
  }
}

// ---------------------------------------------------------------------------
extern "C" void kernel_launch(void* const* d_in, const int* in_sizes, int n_in,
                              void* d_out, int out_size, void* d_ws,
                              size_t ws_size, hipStream_t stream) {
  (void)in_sizes; (void)n_in; (void)out_size; (void)ws_size;
  const float* feat = (const float*)d_in[0];
  const float* out  = (const float*)d_in[1];
  const float* w1   = (const float*)d_in[2];
  const float* b1   = (const float*)d_in[3];
  const float* w2   = (const float*)d_in[4];
  const float* b2   = (const float*)d_in[5];
  const int* index  = (const int*)d_in[6];

  float* ws   = (float*)d_ws;
  float* f1T  = ws;                                   // 2*4096*24 = 196608
  float* f2   = ws + 196608;                          // 2*21*4096 = 172032
  float* otT  = ws + 196608 + 172032;                 // 196608

  float* out0     = (float*)d_out;                    // 2*128*128*128
  float* corr_out = out0 + (size_t)NB * 128 * 128 * 128;  // 2*21*4096
  // partial slabs: 16 * 2 * 21 * 4096 floats = 10.8 MB, parked inside the
  // out0 region (16.8 MB) -- consumed by k_reduce before k_norm writes out0.
  float* part = out0;

  k_feat<<<dim3(HW / FQT, 2), 256, 0, stream>>>(feat, w1, b1, w2, b2, f1T, f2);
  k_statsoutr<<<dim3(HW / PT, 2), 256, 0, stream>>>(f1T, f2, out, otT);
  k_corr8<<<dim3(16, PSPLIT, 2), 256, 0, stream>>>(f1T, f2, otT, part);
  k_reduce<<<dim3(672), 256, 0, stream>>>(part, corr_out);
  k_norm<<<dim3(128, 2), 1024, 0, stream>>>(f1T, f2, index, out0);
}

// Round 19
// 177.714 us; speedup vs baseline: 1.1130x; 1.0335x over previous
//
#include <hip/hip_runtime.h>
#include <math.h>

#define NCL 21
#define CIN 256
#define HW 4096
#define PADK 24
#define NB 2

static __device__ __forceinline__ float fastrcp(float x) {
  return __builtin_amdgcn_rcpf(x);
}

// ---------------------------------------------------------------------------
// Kernel A (v1, R12-proven): f1/f2 = 1x1 conv (w @ feat + b). f1 rows
// PRE-SCALED by 1/sqrt(21). Block = 16 q x 16 c-chunks; LDS reduction.
// R17's single-variable test proved v1 == v2 (feat is not residency-bound).
#define QT 16
#define CCH 16
__global__ __launch_bounds__(256) void k_feat(
    const float* __restrict__ feat, const float* __restrict__ w1,
    const float* __restrict__ b1, const float* __restrict__ w2,
    const float* __restrict__ b2, float* __restrict__ f1T,
    float* __restrict__ f2) {
  const int t = threadIdx.x;
  const int qi = t & 15, ch = t >> 4;  // 16 chunks of 16 channels
  const int n = blockIdx.y;
  const int q = blockIdx.x * QT + qi;
  const int c0 = ch * CCH;
  const float* fp = feat + ((size_t)n * CIN + c0) * HW + q;
  float a1[NCL], a2[NCL];
#pragma unroll
  for (int k = 0; k < NCL; ++k) { a1[k] = 0.f; a2[k] = 0.f; }
#pragma unroll
  for (int cc = 0; cc < CCH; ++cc) {
    float v = fp[(size_t)cc * HW];
#pragma unroll
    for (int k = 0; k < NCL; ++k) {  // w reads thread-uniform -> s_load
      a1[k] = fmaf(v, w1[k * CIN + c0 + cc], a1[k]);
      a2[k] = fmaf(v, w2[k * CIN + c0 + cc], a2[k]);
    }
  }
  __shared__ float p1[CCH][QT][NCL];
  __shared__ float p2[CCH][QT][NCL];
#pragma unroll
  for (int k = 0; k < NCL; ++k) { p1[ch][qi][k] = a1[k]; p2[ch][qi][k] = a2[k]; }
  __syncthreads();
  const float SCALE = 1.0f / sqrtf(21.0f);
  for (int o = t; o < QT * NCL; o += 256) {
    int qq = o & 15, k = o >> 4;
    float s1 = b1[k], s2 = b2[k];
#pragma unroll
    for (int c = 0; c < CCH; ++c) { s1 += p1[c][qq][k]; s2 += p2[c][qq][k]; }
    int qg = blockIdx.x * QT + qq;
    f1T[((size_t)n * HW + qg) * PADK + k] = s1 * SCALE;  // pre-scaled
    f2[((size_t)n * NCL + k) * HW + qg] = s2;
  }
}

// ---------------------------------------------------------------------------
// Kernel C (v4, R12-proven): per block = (8 p-rows, n), all 4096 q in-block,
// then the k_outr epilogue for the same 8 p. q=2 (float2) is the only PT=8
// variant that fits VGPR <= 128 (R7/R8/R10/R11: all q=4 variants hit the
// >128 cliff where waves/SIMD halve).
#define PT 8
__global__ __launch_bounds__(256) void k_statsoutr(
    const float* __restrict__ f1T, const float* __restrict__ f2,
    const float* __restrict__ out, float* __restrict__ otT) {
  __shared__ float srow[PT * PADK];  // 8 rows * 24 floats = 768 B
  __shared__ float red[4][PT];
  __shared__ float linv[PT];
  const int t = threadIdx.x;
  const int n = blockIdx.y;
  const int pbase = blockIdx.x * PT;
  if (t < PT * PADK / 4) {
    ((float4*)srow)[t] =
        ((const float4*)(f1T + ((size_t)n * HW + pbase) * PADK))[t];
  }
  __syncthreads();
  const float* f2n = f2 + (size_t)n * NCL * HW;
  float sums[PT];
#pragma unroll
  for (int p = 0; p < PT; ++p) sums[p] = 0.f;
  for (int qc = 0; qc < 8; ++qc) {
    const int q0 = qc * 512 + t * 2;
    float2 dp[PT];  // dot partials: 16 VGPR
#pragma unroll
    for (int p = 0; p < PT; ++p) dp[p] = make_float2(0.f, 0.f);
#pragma unroll
    for (int g = 0; g < 5; ++g) {  // k = 4g .. 4g+3
      float2 fg0 = *(const float2*)(f2n + (size_t)(4 * g + 0) * HW + q0);
      float2 fg1 = *(const float2*)(f2n + (size_t)(4 * g + 1) * HW + q0);
      float2 fg2 = *(const float2*)(f2n + (size_t)(4 * g + 2) * HW + q0);
      float2 fg3 = *(const float2*)(f2n + (size_t)(4 * g + 3) * HW + q0);
#pragma unroll
      for (int p = 0; p < PT; ++p) {
        float4 ag = *(const float4*)(srow + p * PADK + 4 * g);
        dp[p].x = fmaf(ag.x, fg0.x, dp[p].x);
        dp[p].y = fmaf(ag.x, fg0.y, dp[p].y);
        dp[p].x = fmaf(ag.y, fg1.x, dp[p].x);
        dp[p].y = fmaf(ag.y, fg1.y, dp[p].y);
        dp[p].x = fmaf(ag.z, fg2.x, dp[p].x);
        dp[p].y = fmaf(ag.z, fg2.y, dp[p].y);
        dp[p].x = fmaf(ag.w, fg3.x, dp[p].x);
        dp[p].y = fmaf(ag.w, fg3.y, dp[p].y);
      }
    }
    {  // k = 20 tail
      float2 f20 = *(const float2*)(f2n + (size_t)20 * HW + q0);
#pragma unroll
      for (int p = 0; p < PT; ++p) {
        float a20 = srow[p * PADK + 20];
        dp[p].x = fmaf(a20, f20.x, dp[p].x);
        dp[p].y = fmaf(a20, f20.y, dp[p].y);
      }
    }
#pragma unroll
    for (int p = 0; p < PT; ++p)
      sums[p] += __expf(dp[p].x) + __expf(dp[p].y);
  }
  const int wave = t >> 6, lane = t & 63;
#pragma unroll
  for (int p = 0; p < PT; ++p) {
    float s = sums[p];
    for (int off = 32; off > 0; off >>= 1) s += __shfl_xor(s, off, 64);
    if (lane == 0) red[wave][p] = s;
  }
  __syncthreads();
  if (t < PT) {
    float tot = red[0][t] + red[1][t] + red[2][t] + red[3][t];
    linv[t] = fastrcp(tot);
  }
  __syncthreads();
  // k_outr epilogue for the 8 p of this block: 8*21 = 168 outputs.
  for (int o = t; o < PT * NCL; o += 256) {
    int pl = o & 7, c = o >> 3;
    int pg = pbase + pl;
    int i = pg >> 6, j = pg & 63;
    double sy = (double)i * (127.0 / 63.0);
    double sx = (double)j * (127.0 / 63.0);
    int y0 = (int)sy, x0 = (int)sx;
    float wy = (float)(sy - y0), wx = (float)(sx - x0);
    int y1 = min(y0 + 1, 127), x1 = min(x0 + 1, 127);
    const float* src = out + ((size_t)n * NCL + c) * (128 * 128);
    float v00 = src[y0 * 128 + x0], v10 = src[y1 * 128 + x0];
    float v01 = src[y0 * 128 + x1], v11 = src[y1 * 128 + x1];
    float r0 = v00 * (1.f - wy) + v10 * wy;
    float r1 = v01 * (1.f - wy) + v11 * wy;
    float val = r0 * (1.f - wx) + r1 * wx;
    otT[((size_t)n * HW + pg) * PADK + c] = val * linv[pl];
  }
}

// ---------------------------------------------------------------------------
// Kernel D (v8, R9-proven): DPS=256 / 512 blocks = 2 blocks/CU single round.
// Closed-form: 12 broadcast-ds issues per p-iter = ~25.6 us/CU LDS-issue +
// ~20 us VALU, serialized (ds feeds FMA directly; 2 waves/SIMD can't
// overlap) = the measured 46. Q=8 would halve ds but needs >256 VGPR; more
// waves are LDS-capped. Structural optimum of this decomposition.
#define PSPLIT 16
#define DPS 256
__global__ __launch_bounds__(256) void k_corr8(
    const float* __restrict__ f1T, const float* __restrict__ f2,
    const float* __restrict__ otT, float* __restrict__ part) {
  __shared__ float smem[2 * DPS * PADK];  // 48 KB: sf1 | sot
  float* sf1 = smem;
  float* sot = smem + DPS * PADK;
  const int t = threadIdx.x;  // 0..255
  const int lane = t & 63, wid = t >> 6;
  const int n = blockIdx.z, pb = blockIdx.y;
  const int pbase = pb * DPS;
  {
    const float4* gf = (const float4*)(f1T + ((size_t)n * HW + pbase) * PADK);
    const float4* go = (const float4*)(otT + ((size_t)n * HW + pbase) * PADK);
    float4* sa = (float4*)sf1;
    float4* sb = (float4*)sot;
#pragma unroll
    for (int i = 0; i < DPS * (PADK / 4) / 256; ++i) {
      sa[t + i * 256] = gf[t + i * 256];
      sb[t + i * 256] = go[t + i * 256];
    }
  }
  __syncthreads();
  const int q = blockIdx.x * 256 + lane * 4;
  const float* f2n = f2 + (size_t)n * NCL * HW;
  float4 fq[NCL];
#pragma unroll
  for (int k = 0; k < NCL; ++k)
    fq[k] = *(const float4*)(f2n + (size_t)k * HW + q);
  float4 acc[NCL];
#pragma unroll
  for (int k = 0; k < NCL; ++k) acc[k] = make_float4(0.f, 0.f, 0.f, 0.f);
  const int plo = wid * (DPS / 4);
  const int phi = plo + (DPS / 4);
#pragma unroll 2
  for (int p = plo; p < phi; ++p) {
    const float4* r1 = (const float4*)(sf1 + p * PADK);
    float a[NCL];
    *(float4*)(a + 0) = r1[0];
    *(float4*)(a + 4) = r1[1];
    *(float4*)(a + 8) = r1[2];
    *(float4*)(a + 12) = r1[3];
    *(float4*)(a + 16) = r1[4];
    a[20] = ((const float*)r1)[20];
    float d0 = 0.f, d1 = 0.f, d2 = 0.f, d3 = 0.f;  // 4 independent chains
#pragma unroll
    for (int k = 0; k < NCL; ++k) {
      d0 = fmaf(a[k], fq[k].x, d0);
      d1 = fmaf(a[k], fq[k].y, d1);
      d2 = fmaf(a[k], fq[k].z, d2);
      d3 = fmaf(a[k], fq[k].w, d3);
    }
    float w0 = __expf(d0), w1 = __expf(d1), w2 = __expf(d2), w3 = __expf(d3);
    const float4* ro = (const float4*)(sot + p * PADK);
    float o[NCL];
    *(float4*)(o + 0) = ro[0];
    *(float4*)(o + 4) = ro[1];
    *(float4*)(o + 8) = ro[2];
    *(float4*)(o + 12) = ro[3];
    *(float4*)(o + 16) = ro[4];
    o[20] = ((const float*)ro)[20];
#pragma unroll
    for (int k = 0; k < NCL; ++k) {
      acc[k].x = fmaf(o[k], w0, acc[k].x);
      acc[k].y = fmaf(o[k], w1, acc[k].y);
      acc[k].z = fmaf(o[k], w2, acc[k].z);
      acc[k].w = fmaf(o[k], w3, acc[k].w);
    }
  }
  // 3-round ping-pong combine through the (now dead) LDS tile.
  __syncthreads();  // all ds reads of sf1/sot done; safe to reuse smem
  float4* sbuf = (float4*)smem;
  if (wid == 1) {
#pragma unroll
    for (int c = 0; c < NCL; ++c) sbuf[c * 64 + lane] = acc[c];
  }
  __syncthreads();
  if (wid == 0) {
#pragma unroll
    for (int c = 0; c < NCL; ++c) {
      float4 v = sbuf[c * 64 + lane];
      acc[c].x += v.x; acc[c].y += v.y; acc[c].z += v.z; acc[c].w += v.w;
    }
  }
  __syncthreads();
  if (wid == 3) {
#pragma unroll
    for (int c = 0; c < NCL; ++c) sbuf[c * 64 + lane] = acc[c];
  }
  __syncthreads();
  if (wid == 2) {
#pragma unroll
    for (int c = 0; c < NCL; ++c) {
      float4 v = sbuf[c * 64 + lane];
      acc[c].x += v.x; acc[c].y += v.y; acc[c].z += v.z; acc[c].w += v.w;
    }
  }
  __syncthreads();
  if (wid == 2) {
#pragma unroll
    for (int c = 0; c < NCL; ++c) sbuf[c * 64 + lane] = acc[c];
  }
  __syncthreads();
  if (wid == 0) {
    float* po = part + ((size_t)pb * NB + n) * NCL * HW + q;
#pragma unroll
    for (int c = 0; c < NCL; ++c) {
      float4 v = sbuf[c * 64 + lane];
      v.x += acc[c].x; v.y += acc[c].y; v.z += acc[c].z; v.w += acc[c].w;
      *(float4*)(po + (size_t)c * HW) = v;
    }
  }
}

// ---------------------------------------------------------------------------
// Kernel D2 (R12-proven): corr_out = sum over the 16 slabs. 672 blocks.
__global__ __launch_bounds__(256) void k_reduce(
    const float* __restrict__ part, float* __restrict__ corr_out) {
  const int idx = blockIdx.x * 256 + threadIdx.x;  // NB*NCL*HW = 672*256
  const float* p = part + idx;
  float s = 0.f;
#pragma unroll
  for (int pb = 0; pb < PSPLIT; ++pb)
    s += p[(size_t)pb * (NB * NCL * HW)];
  corr_out[idx] = s;
}

// ---------------------------------------------------------------------------
// Kernel E (R12-proven): per sampled row (i, n), 1024 threads (16 waves =
// 4 waves/SIMD at 1 block/CU). Row compute in one pass, upsample 16 px/
// thread, min/max over 16 waves, booleans out. Runs after k_reduce (slabs
// alias out0).
__global__ __launch_bounds__(1024) void k_norm(
    const float* __restrict__ f1T, const float* __restrict__ f2,
    const int* __restrict__ index, float* __restrict__ out0) {
  __shared__ float row[HW];
  __shared__ float redmn[16], redmx[16];
  __shared__ float wt[128];
  __shared__ int it[128];
  const int t = threadIdx.x;  // 0..1023
  const int i = blockIdx.x;
  const int n = blockIdx.y;
  if (t < 128) {
    double s = (double)t * (63.0 / 127.0);
    int i0 = (int)s;
    wt[t] = (float)(s - i0);
    it[t] = i0;
  }
  int p = index[i];
  p = max(0, min(p, HW - 1));
  const float* f1p = f1T + ((size_t)n * HW + p) * PADK;  // uniform -> s_load
  float a[NCL];
#pragma unroll
  for (int k = 0; k < NCL; ++k) a[k] = f1p[k];
  const float* f2n = f2 + (size_t)n * NCL * HW;
  {
    const int q0 = t * 4;  // 1024 threads x 4 = all 4096 q in one pass
    float d0 = 0.f, d1 = 0.f, d2 = 0.f, d3 = 0.f;
#pragma unroll
    for (int k = 0; k < NCL; ++k) {
      float4 f = *(const float4*)(f2n + (size_t)k * HW + q0);
      d0 = fmaf(a[k], f.x, d0);
      d1 = fmaf(a[k], f.y, d1);
      d2 = fmaf(a[k], f.z, d2);
      d3 = fmaf(a[k], f.w, d3);
    }
    *(float4*)(row + q0) =
        make_float4(__expf(d0), __expf(d1), __expf(d2), __expf(d3));
  }
  __syncthreads();
  float vv[16];
  float lmn = 1e30f, lmx = -1e30f;
#pragma unroll
  for (int j = 0; j < 16; ++j) {
    int pix = t + j * 1024;
    int yy = pix >> 7, xx = pix & 127;
    int y0 = it[yy], x0 = it[xx];
    float wy = wt[yy], wx = wt[xx];
    int y1 = min(y0 + 1, 63), x1 = min(x0 + 1, 63);
    float r0 = row[y0 * 64 + x0] * (1.f - wy) + row[y1 * 64 + x0] * wy;
    float r1 = row[y0 * 64 + x1] * (1.f - wy) + row[y1 * 64 + x1] * wy;
    float v = r0 * (1.f - wx) + r1 * wx;
    vv[j] = v;
    lmn = fminf(lmn, v);
    lmx = fmaxf(lmx, v);
  }
  for (int off = 32; off > 0; off >>= 1) {
    lmn = fminf(lmn, __shfl_xor(lmn, off, 64));
    lmx = fmaxf(lmx, __shfl_xor(lmx, off, 64));
  }
  const int wave = t >> 6, lane = t & 63;
  if (lane == 0) { redmn[wave] = lmn; redmx[wave] = lmx; }
  __syncthreads();
  float mn = redmn[0], mx = redmx[0];
#pragma unroll
  for (int w = 1; w < 16; ++w) {
    mn = fminf(mn, redmn[w]);
    mx = fmaxf(mx, redmx[w]);
  }
  float rng = mx - mn;
  float* slot = out0 + ((size_t)n * 128 + i) * (128 * 128);
#pragma unroll
  for (int j = 0; j < 16; ++j) {
    int pix = t + j * 1024;
    float nrm = (vv[j] - mn) / rng;
    slot[pix] = (nrm > 0.5f) ? 1.0f : 0.0f;
  }
}

// ---------------------------------------------------------------------------
extern "C" void kernel_launch(void* const* d_in, const int* in_sizes, int n_in,
                              void* d_out, int out_size, void* d_ws,
                              size_t ws_size, hipStream_t stream) {
  (void)in_sizes; (void)n_in; (void)out_size; (void)ws_size;
  const float* feat = (const float*)d_in[0];
  const float* out  = (const float*)d_in[1];
  const float* w1   = (const float*)d_in[2];
  const float* b1   = (const float*)d_in[3];
  const float* w2   = (const float*)d_in[4];
  const float* b2   = (const float*)d_in[5];
  const int* index  = (const int*)d_in[6];

  float* ws   = (float*)d_ws;
  float* f1T  = ws;                                   // 2*4096*24 = 196608
  float* f2   = ws + 196608;                          // 2*21*4096 = 172032
  float* otT  = ws + 196608 + 172032;                 // 196608

  float* out0     = (float*)d_out;                    // 2*128*128*128
  float* corr_out = out0 + (size_t)NB * 128 * 128 * 128;  // 2*21*4096
  // partial slabs: 16 * 2 * 21 * 4096 floats = 10.8 MB, parked inside the
  // out0 region (16.8 MB) -- consumed by k_reduce before k_norm writes out0.
  float* part = out0;

  k_feat<<<dim3(HW / QT, 2), 256, 0, stream>>>(feat, w1, b1, w2, b2, f1T, f2);
  k_statsoutr<<<dim3(HW / PT, 2), 256, 0, stream>>>(f1T, f2, out, otT);
  k_corr8<<<dim3(16, PSPLIT, 2), 256, 0, stream>>>(f1T, f2, otT, part);
  k_reduce<<<dim3(672), 256, 0, stream>>>(part, corr_out);
  k_norm<<<dim3(128, 2), 1024, 0, stream>>>(f1T, f2, index, out0);
}